// Round 5
// baseline (291.915 us; speedup 1.0000x reference)
//
#include <hip/hip_runtime.h>
#include <stdint.h>

#define D_EMB 1024
#define NBATCH 8
#define SEQ 2048
#define MTOT (NBATCH*SEQ)   // 16384

typedef __attribute__((ext_vector_type(8))) short short8;
typedef __attribute__((ext_vector_type(4))) float f32x4;

__device__ __forceinline__ ushort bf16r(float x) {
  union { float f; uint32_t u; } c; c.f = x;
  return (ushort)((c.u + 0x7fffu + ((c.u >> 16) & 1u)) >> 16);
}

// async 16B/lane global->LDS (LDS dest must be wave-uniform base + lane*16)
__device__ __forceinline__ void cp16(const ushort* g, ushort* l) {
  __builtin_amdgcn_global_load_lds(
      (const __attribute__((address_space(1))) void*)g,
      (__attribute__((address_space(3))) void*)l, 16, 0, 0);
}

// merged: blocks <4096: wave-per-row cvt x->bf16 + vw[row]=x.wv_eff+sc[1]
//         blocks >=4096: cvt Wattn rows 0..2047 -> bf16 (q,k weights)
__global__ __launch_bounds__(256) void cvt_all(
    const float4* __restrict__ x4, const float4* __restrict__ W4,
    const float4* __restrict__ wv4, const float* __restrict__ sc,
    ushort* __restrict__ xb, ushort* __restrict__ wqkb, float* __restrict__ vw) {
  int tid = threadIdx.x;
  if (blockIdx.x < 4096) {
    int wave = tid >> 6, lane = tid & 63;
    long row = (long)blockIdx.x * 4 + wave;
    const float4* xr = x4 + row * 256;
    ushort* xo = xb + row * D_EMB;
    float s = 0.f;
    #pragma unroll
    for (int i = 0; i < 4; i++) {
      int idx = lane + i * 64;
      float4 v = xr[idx];
      float4 w = wv4[idx];
      *(ushort4*)(xo + idx * 4) = make_ushort4(bf16r(v.x), bf16r(v.y), bf16r(v.z), bf16r(v.w));
      s += v.x * w.x + v.y * w.y + v.z * w.z + v.w * w.w;
    }
    #pragma unroll
    for (int off = 32; off; off >>= 1) s += __shfl_xor(s, off);
    if (lane == 0) vw[row] = s + sc[1];
  } else {
    long base = (long)(blockIdx.x - 4096) * 1024 + tid;   // in float4 units
    #pragma unroll
    for (int i = 0; i < 4; i++) {
      long idx = base + i * 256;
      float4 v = W4[idx];
      *(ushort4*)(wqkb + idx * 4) = make_ushort4(bf16r(v.x), bf16r(v.y), bf16r(v.z), bf16r(v.w));
    }
  }
}

// init: b0 zero w_eff, b1 zero wv_eff, b2 sc[0]=bp.Wfc+bfc, b3..34 zero num/den (32768 f32)
__global__ void init_kernel(const float* __restrict__ bp, const float* __restrict__ Wfc,
                            const float* __restrict__ bfc,
                            float* __restrict__ w_eff, float* __restrict__ wv_eff,
                            float* __restrict__ numden, float* __restrict__ sc) {
  int tid = threadIdx.x;
  int b = blockIdx.x;
  if (b == 0) { w_eff[tid] = 0.f; return; }
  if (b == 1) { wv_eff[tid] = 0.f; return; }
  if (b >= 3) { numden[(long)(b - 3) * 1024 + tid] = 0.f; return; }
  float v = bp[tid] * Wfc[tid];
  int lane = tid & 63, w = tid >> 6;
  #pragma unroll
  for (int off = 32; off; off >>= 1) v += __shfl_xor(v, off);
  __shared__ float red[16];
  if (lane == 0) red[w] = v;
  __syncthreads();
  if (tid == 0) {
    float s = 0.f;
    #pragma unroll
    for (int i = 0; i < 16; i++) s += red[i];
    sc[0] = s + bfc[0];
  }
}

// w_eff[c] += sum over 16-d-chunk of Wfc[d]*Wp[d,c]   grid(4,64)
__global__ void prep1(const float* __restrict__ Wp, const float* __restrict__ Wfc,
                      float* __restrict__ w_eff) {
  int c = blockIdx.x * 256 + threadIdx.x;
  int d0 = blockIdx.y * 16;
  float s = 0.f;
  #pragma unroll
  for (int d = d0; d < d0 + 16; d++) s += Wfc[d] * Wp[(long)d * D_EMB + c];
  atomicAdd(&w_eff[c], s);
}

// grid(4,65): by<64 -> wv_eff[d] += sum over 16-c-chunk of w_eff[c]*Wattn[2048+c, d]
//             by==64 (bx==0) -> sc[1] = sum_c battn[2048+c]*w_eff[c]
__global__ void prep2(const float* __restrict__ Wattn, const float* __restrict__ battn,
                      const float* __restrict__ w_eff, float* __restrict__ wv_eff,
                      float* __restrict__ sc) {
  int tid = threadIdx.x;
  if (blockIdx.y == 64) {
    if (blockIdx.x != 0) return;
    float v = 0.f;
    #pragma unroll
    for (int i = 0; i < 4; i++) { int c = tid + i * 256; v += battn[2048 + c] * w_eff[c]; }
    int lane = tid & 63, w = tid >> 6;
    #pragma unroll
    for (int off = 32; off; off >>= 1) v += __shfl_xor(v, off);
    __shared__ float red[4];
    if (lane == 0) red[w] = v;
    __syncthreads();
    if (tid == 0) sc[1] = red[0] + red[1] + red[2] + red[3];
    return;
  }
  int d = blockIdx.x * 256 + tid;
  int c0 = blockIdx.y * 16;
  float s = 0.f;
  #pragma unroll
  for (int c = c0; c < c0 + 16; c++) s += w_eff[c] * Wattn[(long)(2048 + c) * D_EMB + d];
  atomicAdd(&wv_eff[d], s);
}

// ---------------- NT GEMM: 128x128 tile, BK=64, 16x16x32 bf16 MFMA (R0-proven structure) ----
// FUSED=false: C[m,n] = bf16(scale*acc + bias[n])   (GEMM1 -> qk)
// FUSED=true : per-row partial softmax: num[m] += sum_n exp(scale*acc)*vw[n], den[m] += sum_n exp
// RMODE (XCD maps, flat%8 = XCD per m09 round-robin):
//   0: identity.
//   1: GEMM1 grid(16,128): XCD k owns M-rows [k*2048,(k+1)*2048) -> A panel exclusive per XCD-L2.
//   2: GEMM2 grid(16,16,8): batch z pinned to XCD z (z = flat&7). Per-XCD working set: K-panel
//      4 MB + qk slice 8.4 MB -> staging L2-local. R4 measured FETCH 154->62 MB with this map.
// LDS: [128 rows][8 chunks of 16B], XOR swizzle chunk_stored = chunk ^ (row&7)  (0 conflicts)
template<bool FUSED, int RMODE>
__global__ __launch_bounds__(256, 4) void gemm_nt(
    const ushort* __restrict__ A, long lda, long sAz,
    const ushort* __restrict__ B, long ldb, long sBz,
    ushort* __restrict__ C, long ldc,
    const float* __restrict__ bias, float scale, int K,
    const float* __restrict__ vw, float* __restrict__ num, float* __restrict__ den) {
  __shared__ __align__(16) ushort lds_a[128 * 64];
  __shared__ __align__(16) ushort lds_b[128 * 64];

  int bx, by, z;
  if (RMODE == 1) {
    long f = blockIdx.x + 16L * blockIdx.y;
    int xcd = (int)(f & 7);
    long g = f >> 3;
    bx = (int)(g & 15);
    z = 0; by = xcd * 16 + (int)(g >> 4);
  } else if (RMODE == 2) {
    long f = blockIdx.x + 16L * blockIdx.y + 256L * blockIdx.z;
    z = (int)(f & 7);
    long g = f >> 3;               // [0,256)
    bx = (int)(g & 15);
    by = (int)(g >> 4);
  } else {
    bx = blockIdx.x; by = blockIdx.y; z = blockIdx.z;
  }

  const ushort* Az = A + (long)z * sAz;
  const ushort* Bz = B + (long)z * sBz;
  long m0 = (long)by * 128, n0 = (long)bx * 128;
  int t = threadIdx.x;
  int wave = t >> 6, lane = t & 63;
  int r = lane & 15, q = lane >> 4;
  int wm = (wave & 1) * 64, wn = (wave >> 1) * 64;

  f32x4 acc[4][4] = {};

  // staging: thread owns slots t, t+256, t+512, t+768 -> rows row0 + {0,32,64,96}
  int row0 = t >> 3;
  int kc = (t & 7) ^ (row0 & 7);
  const ushort* Ap = Az + (m0 + row0) * lda + kc * 8;
  const ushort* Bp = Bz + (n0 + row0) * ldb + kc * 8;
  long a32 = 32 * lda, b32 = 32 * ldb;

  int swz = r & 7;

  #pragma unroll 1
  for (int k0 = 0; k0 < K; k0 += 64) {
    if (k0) __syncthreads();
    cp16(Ap + k0,            lds_a + t * 8);
    cp16(Ap + k0 + a32,      lds_a + (t + 256) * 8);
    cp16(Ap + k0 + 2 * a32,  lds_a + (t + 512) * 8);
    cp16(Ap + k0 + 3 * a32,  lds_a + (t + 768) * 8);
    cp16(Bp + k0,            lds_b + t * 8);
    cp16(Bp + k0 + b32,      lds_b + (t + 256) * 8);
    cp16(Bp + k0 + 2 * b32,  lds_b + (t + 512) * 8);
    cp16(Bp + k0 + 3 * b32,  lds_b + (t + 768) * 8);
    __syncthreads();
    #pragma unroll
    for (int kk = 0; kk < 2; kk++) {
      int cidx = (kk * 4 + q) ^ swz;
      short8 af[4], bf[4];
      #pragma unroll
      for (int i = 0; i < 4; i++)
        af[i] = *(const short8*)(lds_a + ((wm + i * 16 + r) * 8 + cidx) * 8);
      #pragma unroll
      for (int j = 0; j < 4; j++)
        bf[j] = *(const short8*)(lds_b + ((wn + j * 16 + r) * 8 + cidx) * 8);
      #pragma unroll
      for (int i = 0; i < 4; i++)
        #pragma unroll
        for (int j = 0; j < 4; j++)
          acc[i][j] = __builtin_amdgcn_mfma_f32_16x16x32_bf16(af[i], bf[j], acc[i][j], 0, 0, 0);
    }
  }

  // C/D layout (verified): row = wm+i*16+q*4+rr, col = wn+j*16+r
  if (!FUSED) {
    #pragma unroll
    for (int i = 0; i < 4; i++) {
      #pragma unroll
      for (int j = 0; j < 4; j++) {
        long col = n0 + wn + j * 16 + r;
        float bj = bias[col];
        #pragma unroll
        for (int rr = 0; rr < 4; rr++) {
          long row = m0 + wm + i * 16 + q * 4 + rr;
          C[row * ldc + col] = bf16r(acc[i][j][rr] * scale + bj);
        }
      }
    }
  } else {
    const float* vwz = vw + (long)z * SEQ + n0;
    float* numz = num + (long)z * SEQ + m0;
    float* denz = den + (long)z * SEQ + m0;
    float vwj[4];
    #pragma unroll
    for (int j = 0; j < 4; j++) vwj[j] = vwz[wn + j * 16 + r];
    #pragma unroll
    for (int i = 0; i < 4; i++) {
      #pragma unroll
      for (int rr = 0; rr < 4; rr++) {
        float sn = 0.f, sd = 0.f;
        #pragma unroll
        for (int j = 0; j < 4; j++) {
          float e = __expf(acc[i][j][rr] * scale);
          sd += e;
          sn += e * vwj[j];
        }
        #pragma unroll
        for (int off = 1; off < 16; off <<= 1) {
          sn += __shfl_xor(sn, off);
          sd += __shfl_xor(sd, off);
        }
        if (r == 0) {
          int row = wm + i * 16 + q * 4 + rr;
          atomicAdd(&numz[row], sn);
          atomicAdd(&denz[row], sd);
        }
      }
    }
  }
}

// out[row] = num[row]/den[row] + c_eff
__global__ __launch_bounds__(256) void finalize(
    const float* __restrict__ num, const float* __restrict__ den,
    const float* __restrict__ sc, float* __restrict__ out) {
  long i = blockIdx.x * 256L + threadIdx.x;
  out[i] = num[i] / den[i] + sc[0];
}

extern "C" void kernel_launch(void* const* d_in, const int* in_sizes, int n_in,
                              void* d_out, int out_size, void* d_ws, size_t ws_size,
                              hipStream_t stream) {
  const float* x     = (const float*)d_in[0];
  const float* Wattn = (const float*)d_in[1];
  const float* battn = (const float*)d_in[2];
  const float* Wproj = (const float*)d_in[3];
  const float* bproj = (const float*)d_in[4];
  const float* Wfc   = (const float*)d_in[5];
  const float* bfc   = (const float*)d_in[6];
  float* out = (float*)d_out;

  // ws layout (bytes)
  const size_t OFF_XB    = 0;          // bf16 [16384][1024]  33554432
  const size_t OFF_WQKB  = 33554432;   // bf16 [2048][1024]    4194304
  const size_t OFF_QK    = 37748736;   // bf16 [16384][2048]  67108864
  const size_t OFF_NUM   = 104857600;  // f32  [16384]           65536
  const size_t OFF_DEN   = 104923136;  // f32  [16384]           65536
  const size_t OFF_VW    = 104988672;  // f32  [16384]           65536
  const size_t OFF_WEFF  = 105054208;  // f32  [1024]
  const size_t OFF_WVEFF = 105058304;  // f32  [1024]
  const size_t OFF_SC    = 105062400;  // f32  [2] {c_eff, vb_eff}
  const size_t NEED      = 105062408;
  if (ws_size < NEED) return;

  char* ws = (char*)d_ws;
  ushort* xb    = (ushort*)(ws + OFF_XB);
  ushort* wqkb  = (ushort*)(ws + OFF_WQKB);
  ushort* qk    = (ushort*)(ws + OFF_QK);
  float* num    = (float*)(ws + OFF_NUM);
  float* den    = (float*)(ws + OFF_DEN);
  float* vw     = (float*)(ws + OFF_VW);
  float* w_eff  = (float*)(ws + OFF_WEFF);
  float* wv_eff = (float*)(ws + OFF_WVEFF);
  float* sc     = (float*)(ws + OFF_SC);

  init_kernel<<<dim3(35), dim3(1024), 0, stream>>>(bproj, Wfc, bfc, w_eff, wv_eff, num, sc);
  prep1<<<dim3(4, 64), dim3(256), 0, stream>>>(Wproj, Wfc, w_eff);
  prep2<<<dim3(4, 65), dim3(256), 0, stream>>>(Wattn, battn, w_eff, wv_eff, sc);

  cvt_all<<<dim3(4096 + 512), dim3(256), 0, stream>>>(
      (const float4*)x, (const float4*)Wattn, (const float4*)wv_eff, sc, xb, wqkb, vw);

  // GEMM1 (RMODE=1): qk[m, n] = bf16( x[m,:] . Wattn[n,:] + battn[n] ), n in [0,2048)
  gemm_nt<false, 1><<<dim3(16, 128, 1), dim3(256), 0, stream>>>(
      xb, (long)D_EMB, 0L, wqkb, (long)D_EMB, 0L,
      qk, 2048L, battn, 1.0f, D_EMB, nullptr, nullptr, nullptr);

  // GEMM2 (RMODE=2, batch z pinned to XCD z): fused num/den partial softmax sums
  gemm_nt<true, 2><<<dim3(16, 16, NBATCH), dim3(256), 0, stream>>>(
      qk, 2048L, (long)SEQ * 2048, qk + 1024, 2048L, (long)SEQ * 2048,
      nullptr, 0L, nullptr, 0.03125f, D_EMB, vw, num, den);

  finalize<<<dim3(64), dim3(256), 0, stream>>>(num, den, sc, out);
}

// Round 6
// 260.780 us; speedup vs baseline: 1.1194x; 1.1194x over previous
//
#include <hip/hip_runtime.h>
#include <stdint.h>

#define D_EMB 1024
#define NBATCH 8
#define SEQ 2048
#define MTOT (NBATCH*SEQ)   // 16384

typedef __attribute__((ext_vector_type(8))) short short8;
typedef __attribute__((ext_vector_type(4))) float f32x4;

__device__ __forceinline__ ushort bf16r(float x) {
  union { float f; uint32_t u; } c; c.f = x;
  return (ushort)((c.u + 0x7fffu + ((c.u >> 16) & 1u)) >> 16);
}

// async 16B/lane global->LDS (LDS dest must be wave-uniform base + lane*16)
__device__ __forceinline__ void cp16(const ushort* g, ushort* l) {
  __builtin_amdgcn_global_load_lds(
      (const __attribute__((address_space(1))) void*)g,
      (__attribute__((address_space(3))) void*)l, 16, 0, 0);
}

// ---------------- D1: cvt_w + init ----------------
// blocks 0..511: 64x64 LDS-transpose-convert Wattn rows [0,2048) -> wt[c][d] = bf16(Wattn[d][c])
//   (wt: [1024 rows c][2048 cols d]; wqT = cols [0,1024), wkT = cols [1024,2048))
// block 512: zero w_eff/wv_eff/v_eff; block 513: sc[0] = bproj.Wfc + bfc; 514..545: zero num/den
__global__ __launch_bounds__(256) void cvt_w(
    const float4* __restrict__ Wattn4, const float* __restrict__ bproj,
    const float* __restrict__ Wfc, const float* __restrict__ bfc,
    ushort* __restrict__ wt, float* __restrict__ w_eff, float* __restrict__ wv_eff,
    float* __restrict__ v_eff, float4* __restrict__ numden4, float* __restrict__ sc) {
  int tid = threadIdx.x;
  int b = blockIdx.x;
  __shared__ ushort lt[64][68];     // +4 pad: transposed col reads spread banks
  __shared__ float red[4];
  if (b < 512) {
    int td = b & 31, tc = b >> 5;   // d-tile [0,32), c-tile [0,16)
    #pragma unroll
    for (int rep = 0; rep < 4; rep++) {
      int i = (tid >> 4) + rep * 16;          // d_local
      int jj = tid & 15;                      // float4 group in c
      float4 v = Wattn4[(long)(td * 64 + i) * 256 + tc * 16 + jj];
      lt[i][jj * 4 + 0] = bf16r(v.x);
      lt[i][jj * 4 + 1] = bf16r(v.y);
      lt[i][jj * 4 + 2] = bf16r(v.z);
      lt[i][jj * 4 + 3] = bf16r(v.w);
    }
    __syncthreads();
    #pragma unroll
    for (int rep = 0; rep < 2; rep++) {
      int c = (tid >> 3) + rep * 32;          // c_local
      int d0 = (tid & 7) * 8;                 // d_local base
      short8 o;
      #pragma unroll
      for (int k = 0; k < 8; k++) o[k] = (short)lt[d0 + k][c];
      *(short8*)(wt + (long)(tc * 64 + c) * 2048 + td * 64 + d0) = o;
    }
    return;
  }
  int b2 = b - 512;
  if (b2 == 0) {
    for (int i = tid; i < 1024; i += 256) { w_eff[i] = 0.f; wv_eff[i] = 0.f; v_eff[i] = 0.f; }
    return;
  }
  if (b2 == 1) {
    float v = 0.f;
    #pragma unroll
    for (int i = 0; i < 4; i++) { int c = tid + i * 256; v += bproj[c] * Wfc[c]; }
    int lane = tid & 63, w = tid >> 6;
    #pragma unroll
    for (int off = 32; off; off >>= 1) v += __shfl_xor(v, off);
    if (lane == 0) red[w] = v;
    __syncthreads();
    if (tid == 0) sc[0] = red[0] + red[1] + red[2] + red[3] + bfc[0];
    return;
  }
  // b2 in [2,34): zero num/den (32768 f32 = 8192 float4)
  numden4[(long)(b2 - 2) * 256 + tid] = make_float4(0.f, 0.f, 0.f, 0.f);
}

// D2: grid(4,128): y<64: w_eff[c] += sum_{16-d chunk} Wfc[d]*Wproj[d,c]
//                  y>=64: v_eff[c] += sum_{16-d chunk} battn[d]*Wattn[1024+d, c]   (v = Wk^T bq)
__global__ void prep1(const float* __restrict__ Wp, const float* __restrict__ Wfc,
                      const float* __restrict__ Wattn, const float* __restrict__ battn,
                      float* __restrict__ w_eff, float* __restrict__ v_eff) {
  int c = blockIdx.x * 256 + threadIdx.x;
  if (blockIdx.y < 64) {
    int d0 = blockIdx.y * 16;
    float s = 0.f;
    #pragma unroll
    for (int d = d0; d < d0 + 16; d++) s += Wfc[d] * Wp[(long)d * D_EMB + c];
    atomicAdd(&w_eff[c], s);
  } else {
    int d0 = (blockIdx.y - 64) * 16;
    float s = 0.f;
    #pragma unroll
    for (int d = d0; d < d0 + 16; d++) s += battn[d] * Wattn[(long)(1024 + d) * D_EMB + c];
    atomicAdd(&v_eff[c], s);
  }
}

// D3 grid(4,65): by<64 -> wv_eff[d] += sum over 16-c-chunk of w_eff[c]*Wattn[2048+c, d]
//                by==64 (bx==0) -> sc[1] = sum_c battn[2048+c]*w_eff[c]
__global__ void prep2(const float* __restrict__ Wattn, const float* __restrict__ battn,
                      const float* __restrict__ w_eff, float* __restrict__ wv_eff,
                      float* __restrict__ sc) {
  int tid = threadIdx.x;
  if (blockIdx.y == 64) {
    if (blockIdx.x != 0) return;
    float v = 0.f;
    #pragma unroll
    for (int i = 0; i < 4; i++) { int c = tid + i * 256; v += battn[2048 + c] * w_eff[c]; }
    int lane = tid & 63, w = tid >> 6;
    #pragma unroll
    for (int off = 32; off; off >>= 1) v += __shfl_xor(v, off);
    __shared__ float red[4];
    if (lane == 0) red[w] = v;
    __syncthreads();
    if (tid == 0) sc[1] = red[0] + red[1] + red[2] + red[3];
    return;
  }
  int d = blockIdx.x * 256 + tid;
  int c0 = blockIdx.y * 16;
  float s = 0.f;
  #pragma unroll
  for (int c = c0; c < c0 + 16; c++) s += w_eff[c] * Wattn[(long)(2048 + c) * D_EMB + d];
  atomicAdd(&wv_eff[d], s);
}

// ---------------- NT GEMM body: 128x128 tile, BK=64, 16x16x32 bf16 MFMA (R0-proven) ----------
// MODE 0: C[m,n] = bf16(acc*scale)                         (Mt-GEMM, GEMM1' -> xm)
// MODE 1: per-row partial softmax with per-col bias bb:
//         e = exp((acc + bb[s])*scale); num[m] += sum e*vw[s]; den[m] += sum e
// LDS: [128 rows][8 chunks of 16B], XOR swizzle chunk_stored = chunk ^ (row&7)  (0 conflicts)
template<int MODE>
__device__ __forceinline__ void gemm_body(
    int bx, int by, int z, ushort* lds_a, ushort* lds_b,
    const ushort* __restrict__ A, long lda, long sAz,
    const ushort* __restrict__ B, long ldb, long sBz,
    ushort* __restrict__ C, long ldc, float scale, int K,
    const float* __restrict__ vw, const float* __restrict__ bb,
    float* __restrict__ num, float* __restrict__ den) {
  const ushort* Az = A + (long)z * sAz;
  const ushort* Bz = B + (long)z * sBz;
  long m0 = (long)by * 128, n0 = (long)bx * 128;
  int t = threadIdx.x;
  int wave = t >> 6, lane = t & 63;
  int r = lane & 15, q = lane >> 4;
  int wm = (wave & 1) * 64, wn = (wave >> 1) * 64;

  f32x4 acc[4][4] = {};

  // staging: thread owns slots t, t+256, t+512, t+768 -> rows row0 + {0,32,64,96}
  int row0 = t >> 3;
  int kc = (t & 7) ^ (row0 & 7);
  const ushort* Ap = Az + (m0 + row0) * lda + kc * 8;
  const ushort* Bp = Bz + (n0 + row0) * ldb + kc * 8;
  long a32 = 32 * lda, b32 = 32 * ldb;

  int swz = r & 7;

  #pragma unroll 1
  for (int k0 = 0; k0 < K; k0 += 64) {
    if (k0) __syncthreads();
    cp16(Ap + k0,            lds_a + t * 8);
    cp16(Ap + k0 + a32,      lds_a + (t + 256) * 8);
    cp16(Ap + k0 + 2 * a32,  lds_a + (t + 512) * 8);
    cp16(Ap + k0 + 3 * a32,  lds_a + (t + 768) * 8);
    cp16(Bp + k0,            lds_b + t * 8);
    cp16(Bp + k0 + b32,      lds_b + (t + 256) * 8);
    cp16(Bp + k0 + 2 * b32,  lds_b + (t + 512) * 8);
    cp16(Bp + k0 + 3 * b32,  lds_b + (t + 768) * 8);
    __syncthreads();
    #pragma unroll
    for (int kk = 0; kk < 2; kk++) {
      int cidx = (kk * 4 + q) ^ swz;
      short8 af[4], bf[4];
      #pragma unroll
      for (int i = 0; i < 4; i++)
        af[i] = *(const short8*)(lds_a + ((wm + i * 16 + r) * 8 + cidx) * 8);
      #pragma unroll
      for (int j = 0; j < 4; j++)
        bf[j] = *(const short8*)(lds_b + ((wn + j * 16 + r) * 8 + cidx) * 8);
      #pragma unroll
      for (int i = 0; i < 4; i++)
        #pragma unroll
        for (int j = 0; j < 4; j++)
          acc[i][j] = __builtin_amdgcn_mfma_f32_16x16x32_bf16(af[i], bf[j], acc[i][j], 0, 0, 0);
    }
  }

  // C/D layout (verified): row = wm+i*16+q*4+rr, col = wn+j*16+r
  if (MODE == 0) {
    #pragma unroll
    for (int i = 0; i < 4; i++) {
      #pragma unroll
      for (int j = 0; j < 4; j++) {
        long col = n0 + wn + j * 16 + r;
        #pragma unroll
        for (int rr = 0; rr < 4; rr++) {
          long row = m0 + wm + i * 16 + q * 4 + rr;
          C[row * ldc + col] = bf16r(acc[i][j][rr] * scale);
        }
      }
    }
  } else {
    const float* vwz = vw + (long)z * SEQ + n0;
    const float* bbz = bb + (long)z * SEQ + n0;
    float* numz = num + (long)z * SEQ + m0;
    float* denz = den + (long)z * SEQ + m0;
    float vwj[4], bbj[4];
    #pragma unroll
    for (int j = 0; j < 4; j++) {
      vwj[j] = vwz[wn + j * 16 + r];
      bbj[j] = bbz[wn + j * 16 + r];
    }
    #pragma unroll
    for (int i = 0; i < 4; i++) {
      #pragma unroll
      for (int rr = 0; rr < 4; rr++) {
        float sn = 0.f, sd = 0.f;
        #pragma unroll
        for (int j = 0; j < 4; j++) {
          float e = __expf((acc[i][j][rr] + bbj[j]) * scale);
          sd += e;
          sn += e * vwj[j];
        }
        #pragma unroll
        for (int off = 1; off < 16; off <<= 1) {
          sn += __shfl_xor(sn, off);
          sd += __shfl_xor(sd, off);
        }
        if (r == 0) {
          int row = wm + i * 16 + q * 4 + rr;
          atomicAdd(&numz[row], sn);
          atomicAdd(&denz[row], sd);
        }
      }
    }
  }
}

// D4: merged cvt_x + Mt-GEMM. blocks 0..63: Mt[c'][c] = sum_d wkT[c',d]*wqT[c,d]
//   (A = wt+1024, B = wt, lda=ldb=2048, K=1024, grid-equivalent 8x8) -- runs first, overlaps cvt.
// blocks 64..4159: wave-per-row: xb = bf16(x); vw[row] = x.wv_eff + sc[1]; bb[row] = x.v_eff
__global__ __launch_bounds__(256, 4) void cvt_mt(
    const float4* __restrict__ x4, const float4* __restrict__ wv4,
    const float4* __restrict__ v4, const float* __restrict__ sc,
    ushort* __restrict__ xb, float* __restrict__ vw, float* __restrict__ bb,
    const ushort* __restrict__ wt, ushort* __restrict__ mt) {
  __shared__ __align__(16) ushort lds_a[128 * 64];
  __shared__ __align__(16) ushort lds_b[128 * 64];
  int tid = threadIdx.x;
  if (blockIdx.x < 64) {
    int b = blockIdx.x;
    gemm_body<0>(b & 7, b >> 3, 0, lds_a, lds_b,
                 wt + 1024, 2048L, 0L, wt, 2048L, 0L,
                 mt, 1024L, 1.0f, D_EMB, nullptr, nullptr, nullptr, nullptr);
    return;
  }
  int wave = tid >> 6, lane = tid & 63;
  long row = (long)(blockIdx.x - 64) * 4 + wave;
  const float4* xr = x4 + row * 256;
  ushort* xo = xb + row * D_EMB;
  float s = 0.f, s2 = 0.f;
  #pragma unroll
  for (int i = 0; i < 4; i++) {
    int idx = lane + i * 64;
    float4 v = xr[idx];
    float4 w = wv4[idx];
    float4 u = v4[idx];
    *(ushort4*)(xo + idx * 4) = make_ushort4(bf16r(v.x), bf16r(v.y), bf16r(v.z), bf16r(v.w));
    s  += v.x * w.x + v.y * w.y + v.z * w.z + v.w * w.w;
    s2 += v.x * u.x + v.y * u.y + v.z * u.z + v.w * u.w;
  }
  #pragma unroll
  for (int off = 32; off; off >>= 1) { s += __shfl_xor(s, off); s2 += __shfl_xor(s2, off); }
  if (lane == 0) { vw[row] = s + sc[1]; bb[row] = s2; }
}

// Standalone GEMM kernel.
// RMODE 1 (GEMM1', grid(8,128)): f = bx+8*by; xcd = f&7 (m09 round-robin); XCD k owns
//   by in [16k,16k+16) -> A panel rows [2048k,2048(k+1)) exclusive per XCD-L2; B (Mt, 2MB)
//   L2-resident everywhere.  RMODE 0: identity (GEMM2' -- R5 proved pinning hurts).
template<int MODE, int RMODE>
__global__ __launch_bounds__(256, 4) void gemm_nt(
    const ushort* __restrict__ A, long lda, long sAz,
    const ushort* __restrict__ B, long ldb, long sBz,
    ushort* __restrict__ C, long ldc, float scale, int K,
    const float* __restrict__ vw, const float* __restrict__ bb,
    float* __restrict__ num, float* __restrict__ den) {
  __shared__ __align__(16) ushort lds_a[128 * 64];
  __shared__ __align__(16) ushort lds_b[128 * 64];
  int bx, by, z;
  if (RMODE == 1) {
    int f = (int)(blockIdx.x + 8u * blockIdx.y);
    int xcd = f & 7, g = f >> 3;
    by = xcd * 16 + (g & 15); bx = g >> 4; z = 0;
  } else {
    bx = blockIdx.x; by = blockIdx.y; z = blockIdx.z;
  }
  gemm_body<MODE>(bx, by, z, lds_a, lds_b, A, lda, sAz, B, ldb, sBz,
                  C, ldc, scale, K, vw, bb, num, den);
}

// out[row] = num[row]/den[row] + c_eff
__global__ __launch_bounds__(256) void finalize(
    const float* __restrict__ num, const float* __restrict__ den,
    const float* __restrict__ sc, float* __restrict__ out) {
  long i = blockIdx.x * 256L + threadIdx.x;
  out[i] = num[i] / den[i] + sc[0];
}

extern "C" void kernel_launch(void* const* d_in, const int* in_sizes, int n_in,
                              void* d_out, int out_size, void* d_ws, size_t ws_size,
                              hipStream_t stream) {
  const float* x     = (const float*)d_in[0];
  const float* Wattn = (const float*)d_in[1];
  const float* battn = (const float*)d_in[2];
  const float* Wproj = (const float*)d_in[3];
  const float* bproj = (const float*)d_in[4];
  const float* Wfc   = (const float*)d_in[5];
  const float* bfc   = (const float*)d_in[6];
  float* out = (float*)d_out;

  // ws layout (bytes)
  const size_t OFF_XB    = 0;          // bf16 [16384][1024]  33554432
  const size_t OFF_WT    = 33554432;   // bf16 [1024][2048]    4194304  (Wq^T | Wk^T)
  const size_t OFF_MT    = 37748736;   // bf16 [1024][1024]    2097152  (Mt[c'][c] = Wk^T Wq)
  const size_t OFF_XM    = 39845888;   // bf16 [16384][1024]  33554432  (x . M)
  const size_t OFF_NUM   = 73400320;   // f32  [16384]           65536
  const size_t OFF_DEN   = 73465856;   // f32  [16384]           65536
  const size_t OFF_VW    = 73531392;   // f32  [16384]           65536
  const size_t OFF_BB    = 73596928;   // f32  [16384]           65536  (bb[s] = v.x_s)
  const size_t OFF_WEFF  = 73662464;   // f32  [1024]
  const size_t OFF_WVEFF = 73666560;   // f32  [1024]
  const size_t OFF_VEFF  = 73670656;   // f32  [1024]
  const size_t OFF_SC    = 73674752;   // f32  [2] {c_eff, vb_eff}
  const size_t NEED      = 73674760;
  if (ws_size < NEED) return;

  char* ws = (char*)d_ws;
  ushort* xb    = (ushort*)(ws + OFF_XB);
  ushort* wt    = (ushort*)(ws + OFF_WT);
  ushort* mt    = (ushort*)(ws + OFF_MT);
  ushort* xm    = (ushort*)(ws + OFF_XM);
  float* num    = (float*)(ws + OFF_NUM);
  float* den    = (float*)(ws + OFF_DEN);
  float* vw     = (float*)(ws + OFF_VW);
  float* bb     = (float*)(ws + OFF_BB);
  float* w_eff  = (float*)(ws + OFF_WEFF);
  float* wv_eff = (float*)(ws + OFF_WVEFF);
  float* v_eff  = (float*)(ws + OFF_VEFF);
  float* sc     = (float*)(ws + OFF_SC);

  // D1: transpose-convert Wq/Wk + zero accumulators + sc[0]
  cvt_w<<<dim3(546), dim3(256), 0, stream>>>(
      (const float4*)Wattn, bproj, Wfc, bfc, wt, w_eff, wv_eff, v_eff, (float4*)num, sc);

  // D2: w_eff = Wproj^T Wfc ; v_eff = Wk^T bq
  prep1<<<dim3(4, 128), dim3(256), 0, stream>>>(Wproj, Wfc, Wattn, battn, w_eff, v_eff);

  // D3: wv_eff = Wv^T w_eff ; sc[1] = bv . w_eff
  prep2<<<dim3(4, 65), dim3(256), 0, stream>>>(Wattn, battn, w_eff, wv_eff, sc);

  // D4: Mt-GEMM (blocks 0..63, overlapped) + x->bf16 / vw / bb (blocks 64..4159)
  cvt_mt<<<dim3(64 + 4096), dim3(256), 0, stream>>>(
      (const float4*)x, (const float4*)wv_eff, (const float4*)v_eff, sc, xb, vw, bb, wt, mt);

  // D5 GEMM1': xm[t,c'] = sum_c xb[t,c] * Mt[c',c]   (M=16384, N=1024, K=1024)
  gemm_nt<0, 1><<<dim3(8, 128, 1), dim3(256), 0, stream>>>(
      xb, (long)D_EMB, 0L, mt, (long)D_EMB, 0L,
      xm, (long)D_EMB, 1.0f, D_EMB, nullptr, nullptr, nullptr, nullptr);

  // D6 GEMM2': num/den over exp((xm_t . xb_s + bb[s]) * scale) per batch (identity map)
  gemm_nt<1, 0><<<dim3(16, 16, NBATCH), dim3(256), 0, stream>>>(
      xm, (long)D_EMB, (long)SEQ * D_EMB, xb, (long)D_EMB, (long)SEQ * D_EMB,
      nullptr, 0L, 0.03125f, D_EMB, vw, bb, num, den);

  finalize<<<dim3(64), dim3(256), 0, stream>>>(num, den, sc, out);
}